// Round 4
// baseline (244.981 us; speedup 1.0000x reference)
//
#include <hip/hip_runtime.h>
#include <math.h>

typedef __bf16 bf16;
typedef __attribute__((ext_vector_type(8))) __bf16 bf16x8;
typedef __attribute__((ext_vector_type(4))) __bf16 bf16x4;
typedef __attribute__((ext_vector_type(4))) float f32x4;

#define B_  2
#define S_  2048
#define H_  1024
#define NH_ 16
#define D_  64

__device__ __forceinline__ f32x4 mfma16(bf16x8 a, bf16x8 b, f32x4 c) {
    return __builtin_amdgcn_mfma_f32_16x16x32_bf16(a, b, c, 0, 0, 0);
}

// async global->LDS, 16B per lane; lds dest = wave-uniform base + lane*16
__device__ __forceinline__ void async16(void* lds, const void* g) {
    __builtin_amdgcn_global_load_lds(
        (const __attribute__((address_space(1))) unsigned int*)g,
        (__attribute__((address_space(3))) unsigned int*)lds, 16, 0, 0);
}

// Merged prep: cvt x -> xb, cvt Wqkv -> wqb, build RoPE table tab[s][i]={cos,sin}
__global__ __launch_bounds__(256) void cvt_main(
    const float* __restrict__ x, const float* __restrict__ wqkv,
    bf16* __restrict__ xb, bf16* __restrict__ wqb, float2* __restrict__ tab)
{
    const int bid = blockIdx.x, tid = threadIdx.x;
    if (bid < 4096) {
        int i = bid * 256 + tid;
        f32x4 v = *(const f32x4*)(x + (size_t)i * 4);
        bf16x4 o; o[0]=(bf16)v[0]; o[1]=(bf16)v[1]; o[2]=(bf16)v[2]; o[3]=(bf16)v[3];
        *(bf16x4*)(xb + (size_t)i * 4) = o;
    } else if (bid < 7168) {
        int i = (bid - 4096) * 256 + tid;
        f32x4 v = *(const f32x4*)(wqkv + (size_t)i * 4);
        bf16x4 o; o[0]=(bf16)v[0]; o[1]=(bf16)v[1]; o[2]=(bf16)v[2]; o[3]=(bf16)v[3];
        *(bf16x4*)(wqb + (size_t)i * 4) = o;
    } else {
        int idx = (bid - 7168) * 256 + tid;      // idx = s*32 + i
        int s = idx >> 5, i = idx & 31;
        float f = exp2f((float)i * (-13.287712379549449f / 32.0f));
        float sn, cs;
        sincosf((float)s * f, &sn, &cs);
        tab[idx] = make_float2(cs, sn);
    }
}

// fp32 -> bf16 bulk convert (W_o), 4 elems/thread
__global__ __launch_bounds__(256) void cvt_bf16(const float* __restrict__ src,
                                                bf16* __restrict__ dst, int n4) {
    int i = blockIdx.x * 256 + threadIdx.x;
    if (i >= n4) return;
    f32x4 v = *(const f32x4*)(src + (size_t)i * 4);
    bf16x4 o; o[0]=(bf16)v[0]; o[1]=(bf16)v[1]; o[2]=(bf16)v[2]; o[3]=(bf16)v[3];
    *(bf16x4*)(dst + (size_t)i * 4) = o;
}

// C[M,N] = A[M,K] @ W[N,K]^T, bf16, both tiles via global_load_lds (m97 structure),
// XOR chunk-swizzle phys = logical ^ (row&3).
// EPI=0 (qkv): fused RMSNorm + table-RoPE for q/k; lambda-mix + r-packed
//   transposed store for v. EPI=1: plain fp32 store.
template <int EPI>
__global__ __launch_bounds__(256) void gemm_bt(
    const bf16* __restrict__ A, const bf16* __restrict__ W,
    int M, int N, int K,
    float* __restrict__ outF,
    bf16* __restrict__ qb, bf16* __restrict__ kb, bf16* __restrict__ vtb,
    const float* __restrict__ ve, const float* __restrict__ lambdas,
    const float2* __restrict__ tab)
{
    __shared__ bf16 Al[128][32];
    __shared__ bf16 Bl[128][32];
    const int m0   = blockIdx.y * 128;
    const int n0   = blockIdx.x * 128;
    const int tid  = threadIdx.x;
    const int lane = tid & 63;
    const int w    = tid >> 6;
    const int quad = lane >> 4;
    const int l16  = lane & 15;
    const int wm   = (w >> 1) * 64;
    const int wn   = (w & 1) * 64;
    const int arow = lane >> 2;
    const int achk = (lane & 3) ^ ((lane >> 2) & 3);

    const f32x4 Z4 = {0.f, 0.f, 0.f, 0.f};
    f32x4 acc[4][4];
#pragma unroll
    for (int i = 0; i < 4; ++i)
#pragma unroll
        for (int j = 0; j < 4; ++j) acc[i][j] = Z4;

    for (int k0 = 0; k0 < K; k0 += 32) {
        const bf16* gB = W + (size_t)(n0 + w * 32 + arow) * K + k0 + achk * 8;
        async16(&Bl[w * 32][0], gB);
        async16(&Bl[w * 32 + 16][0], gB + (size_t)16 * K);
        const bf16* gA = A + (size_t)(m0 + w * 32 + arow) * K + k0 + achk * 8;
        async16(&Al[w * 32][0], gA);
        async16(&Al[w * 32 + 16][0], gA + (size_t)16 * K);
        __syncthreads();
        bf16x8 af[4], bfg[4];
#pragma unroll
        for (int i = 0; i < 4; ++i)
            af[i]  = *(const bf16x8*)&Al[wm + i * 16 + l16][(quad ^ (l16 & 3)) * 8];
#pragma unroll
        for (int j = 0; j < 4; ++j)
            bfg[j] = *(const bf16x8*)&Bl[wn + j * 16 + l16][(quad ^ (l16 & 3)) * 8];
#pragma unroll
        for (int i = 0; i < 4; ++i)
#pragma unroll
            for (int j = 0; j < 4; ++j)
                acc[i][j] = mfma16(af[i], bfg[j], acc[i][j]);
        __syncthreads();
    }

    if constexpr (EPI == 1) {
#pragma unroll
        for (int i = 0; i < 4; ++i)
#pragma unroll
            for (int j = 0; j < 4; ++j)
#pragma unroll
                for (int r = 0; r < 4; ++r) {
                    int m = m0 + wm + i * 16 + quad * 4 + r;
                    int n = n0 + wn + j * 16 + l16;
                    outF[(size_t)m * N + n] = acc[i][j][r];
                }
    } else {
        const int nbase = n0 + wn;              // wave-uniform
        const int which = nbase >> 10;          // 0=q 1=k 2=v
        const int h     = (nbase & (H_ - 1)) >> 6;
        if (which < 2) {
            bf16* dst = which ? kb : qb;
#pragma unroll
            for (int i = 0; i < 4; ++i) {
                float ss[4];
#pragma unroll
                for (int r = 0; r < 4; ++r)
                    ss[r] = acc[i][0][r] * acc[i][0][r] + acc[i][1][r] * acc[i][1][r]
                          + acc[i][2][r] * acc[i][2][r] + acc[i][3][r] * acc[i][3][r];
#pragma unroll
                for (int r = 0; r < 4; ++r) {
                    ss[r] += __shfl_xor(ss[r], 1);
                    ss[r] += __shfl_xor(ss[r], 2);
                    ss[r] += __shfl_xor(ss[r], 4);
                    ss[r] += __shfl_xor(ss[r], 8);
                }
#pragma unroll
                for (int r = 0; r < 4; ++r) {
                    int    m   = m0 + wm + i * 16 + quad * 4 + r;
                    int    bb  = m >> 11, s = m & (S_ - 1);
                    float  rms = rsqrtf(ss[r] * (1.0f / 64.0f) + 1.1920929e-07f);
                    float  x0 = acc[i][0][r] * rms, x1 = acc[i][1][r] * rms;
                    float  x2 = acc[i][2][r] * rms, x3 = acc[i][3][r] * rms;
                    float2 t0 = tab[(size_t)s * 32 + l16];        // {cos,sin} i=l16
                    float2 t1 = tab[(size_t)s * 32 + 16 + l16];   // i=l16+16
                    bf16*  bp = dst + ((size_t)(bb * NH_ + h) * S_ + s) * D_;
                    bp[l16]      = (bf16)(x0 * t0.x + x2 * t0.y);
                    bp[16 + l16] = (bf16)(x1 * t1.x + x3 * t1.y);
                    bp[32 + l16] = (bf16)(x2 * t0.x - x0 * t0.y);
                    bp[48 + l16] = (bf16)(x3 * t1.x - x1 * t1.y);
                }
            }
        } else {
            const float l0 = lambdas[0], l1 = lambdas[1];
#pragma unroll
            for (int i = 0; i < 4; ++i) {
                const int m00 = m0 + wm + i * 16 + quad * 4;   // 4 consecutive s
                const int bb  = m00 >> 11, s = m00 & (S_ - 1);
#pragma unroll
                for (int j = 0; j < 4; ++j) {
                    const int d = j * 16 + l16;
                    bf16x4 pk;
#pragma unroll
                    for (int r = 0; r < 4; ++r) {
                        float vm = l0 * acc[i][j][r]
                                 + l1 * ve[(size_t)(m00 + r) * H_ + h * 64 + d];
                        pk[r] = (bf16)vm;
                    }
                    *(bf16x4*)&vtb[((size_t)(bb * NH_ + h) * D_ + d) * S_ + s] = pk;
                }
            }
        }
    }
}

// Flash attention, un-paired: grid (32, B*NH), qt = 31-bx (longest first), 4 blocks/CU.
// Static max=8, swapped-operand QK (scores key-contiguous), double-buffered K/V via
// global_load_lds (prefetch c+1 issued before compute of c), diagonal-only masking.
__global__ __launch_bounds__(256) void attn(
    const bf16* __restrict__ Q, const bf16* __restrict__ Kg,
    const bf16* __restrict__ Vt, bf16* __restrict__ Og)
{
    __shared__ bf16 Kl[2][64][64];
    __shared__ bf16 Vl[2][64][64];
    __shared__ bf16 Pl[4][16][64];

    const int bh   = blockIdx.y;
    const int b    = bh >> 4;
    const int h    = bh & 15;
    const int qt   = gridDim.x - 1 - blockIdx.x;
    const int tid  = threadIdx.x;
    const int lane = tid & 63;
    const int w    = tid >> 6;
    const int quad = lane >> 4;
    const int l16  = lane & 15;
    const int l7   = l16 & 7;

    const bf16* Qp = Q  + (size_t)bh * S_ * D_;
    const bf16* Kp = Kg + (size_t)bh * S_ * D_;
    const bf16* Vp = Vt + (size_t)bh * D_ * S_;

    const int srow = lane >> 3;
    const int schk = (lane & 7) ^ (lane >> 3);
    const f32x4 Z4 = {0.f, 0.f, 0.f, 0.f};
    const float C1 = 0.18033688011112042f;     // 0.125*log2(e)
    const float C2 = -11.541560327111707f;     // -8*log2(e)

    const int qbase = qt * 64 + w * 16;
    const int qi    = qbase + l16;

    bf16x8 qf0 = *(const bf16x8*)(Qp + (size_t)(qbase + l16) * D_ + quad * 8);
    bf16x8 qf1 = *(const bf16x8*)(Qp + (size_t)(qbase + l16) * D_ + 32 + quad * 8);

    f32x4 of[4];
#pragma unroll
    for (int dt = 0; dt < 4; ++dt) of[dt] = Z4;
    float lsum = 0.f;

    auto stage = [&](int p, int kb0) {
        const bf16* gK = Kp + (size_t)(kb0 + w * 16 + srow) * D_ + schk * 8;
        async16(&Kl[p][w * 16][0], gK);
        async16(&Kl[p][w * 16 + 8][0], gK + (size_t)8 * D_);
        const bf16* gV = Vp + (size_t)(w * 16 + srow) * S_ + kb0 + schk * 8;
        async16(&Vl[p][w * 16][0], gV);
        async16(&Vl[p][w * 16 + 8][0], gV + (size_t)8 * S_);
    };

    stage(0, 0);
    const int nch = qt + 1;
    for (int c = 0; c < nch; ++c) {
        const int p   = c & 1;
        const int kb0 = c * 64;
        __syncthreads();                 // buf[p] ready (prefetch aged 1 phase)
        if (c + 1 < nch) stage(p ^ 1, kb0 + 64);

        float ps = 0.f;
        if (c < qt) {                    // strictly below diagonal: no mask
#pragma unroll
            for (int nt = 0; nt < 4; ++nt) {
                bf16x8 kf0 = *(const bf16x8*)&Kl[p][nt * 16 + l16][(quad ^ l7) * 8];
                bf16x8 kf1 = *(const bf16x8*)&Kl[p][nt * 16 + l16][((quad + 4) ^ l7) * 8];
                f32x4 sacc = Z4;
                sacc = mfma16(kf0, qf0, sacc);
                sacc = mfma16(kf1, qf1, sacc);
                bf16x4 pk;
#pragma unroll
                for (int r = 0; r < 4; ++r) {
                    float pv = exp2f(fmaf(sacc[r], C1, C2));
                    ps += pv;
                    pk[r] = (bf16)pv;
                }
                *(bf16x4*)&Pl[w][l16][((nt * 2 + (quad >> 1)) ^ l7) * 8 + (quad & 1) * 4] = pk;
            }
        } else {                         // diagonal chunk: causal mask
#pragma unroll
            for (int nt = 0; nt < 4; ++nt) {
                bf16x8 kf0 = *(const bf16x8*)&Kl[p][nt * 16 + l16][(quad ^ l7) * 8];
                bf16x8 kf1 = *(const bf16x8*)&Kl[p][nt * 16 + l16][((quad + 4) ^ l7) * 8];
                f32x4 sacc = Z4;
                sacc = mfma16(kf0, qf0, sacc);
                sacc = mfma16(kf1, qf1, sacc);
                bf16x4 pk;
#pragma unroll
                for (int r = 0; r < 4; ++r) {
                    int   key = kb0 + nt * 16 + quad * 4 + r;
                    float pv  = (key <= qi) ? exp2f(fmaf(sacc[r], C1, C2)) : 0.f;
                    ps += pv;
                    pk[r] = (bf16)pv;
                }
                *(bf16x4*)&Pl[w][l16][((nt * 2 + (quad >> 1)) ^ l7) * 8 + (quad & 1) * 4] = pk;
            }
        }
        ps += __shfl_xor(ps, 16);
        ps += __shfl_xor(ps, 32);
        lsum += ps;

        bf16x8 pf0 = *(const bf16x8*)&Pl[w][l16][(quad ^ l7) * 8];
        bf16x8 pf1 = *(const bf16x8*)&Pl[w][l16][((quad + 4) ^ l7) * 8];
#pragma unroll
        for (int dt = 0; dt < 4; ++dt) {
            bf16x8 vf0 = *(const bf16x8*)&Vl[p][dt * 16 + l16][(quad ^ l7) * 8];
            bf16x8 vf1 = *(const bf16x8*)&Vl[p][dt * 16 + l16][((quad + 4) ^ l7) * 8];
            of[dt] = mfma16(pf0, vf0, of[dt]);
            of[dt] = mfma16(pf1, vf1, of[dt]);
        }
    }

#pragma unroll
    for (int r = 0; r < 4; ++r) {
        float ld = __shfl(lsum, quad * 4 + r);
        float rl = 1.0f / ld;
        int   qq = qbase + quad * 4 + r;
#pragma unroll
        for (int dt = 0; dt < 4; ++dt)
            Og[((size_t)(b * S_ + qq)) * H_ + h * D_ + dt * 16 + l16] =
                (bf16)(of[dt][r] * rl);
    }
}

extern "C" void kernel_launch(void* const* d_in, const int* in_sizes, int n_in,
                              void* d_out, int out_size, void* d_ws, size_t ws_size,
                              hipStream_t stream)
{
    const float* x       = (const float*)d_in[0];
    const float* ve      = (const float*)d_in[1];
    const float* Wqkv    = (const float*)d_in[2];
    const float* Wo      = (const float*)d_in[3];
    const float* lambdas = (const float*)d_in[4];
    float* out = (float*)d_out;

    // d_out (16 MiB) early-phase scratch: xb [0,8M), wqb [8,14M), rope tab [14,14.5M).
    // All die after gemm1; gemm2 overwrites d_out with the final output.
    // ws (32 MiB): qb [0,8M), kb [8,16M), vtb [16,24M), ao [24,32M);
    // wob reuses [0,2M) after attn retires qb.
    char* od = (char*)d_out;
    char* ws = (char*)d_ws;
    const size_t MB = 1024 * 1024;
    bf16*   xb  = (bf16*)(od);
    bf16*   wqb = (bf16*)(od + 8 * MB);
    float2* tab = (float2*)(od + 14 * MB);
    bf16*   qb  = (bf16*)(ws);
    bf16*   kb  = (bf16*)(ws + 8 * MB);
    bf16*   vtb = (bf16*)(ws + 16 * MB);
    bf16*   ao  = (bf16*)(ws + 24 * MB);
    bf16*   wob = (bf16*)(ws);

    // 1) convert x + W_qkv to bf16, build RoPE table (one kernel)
    cvt_main<<<7424, 256, 0, stream>>>(x, Wqkv, xb, wqb, tab);
    // 2) qkv GEMM, fused RMSNorm + table-RoPE (q,k) + packed lambda-mix (v)
    gemm_bt<0><<<dim3(24, 32), 256, 0, stream>>>(
        xb, wqb, B_ * S_, 3 * H_, H_, nullptr, qb, kb, vtb, ve, lambdas, (const float2*)tab);
    // 3) causal flash attention (un-paired, longest first) -> ao
    attn<<<dim3(32, B_ * NH_), 256, 0, stream>>>(qb, kb, vtb, ao);
    // 4) convert W_o (into retired qb space)
    cvt_bf16<<<1024, 256, 0, stream>>>(Wo, wob, (H_ * H_) / 4);
    // 5) out = ao @ Wo^T (fp32, overwrites d_out)
    gemm_bt<1><<<dim3(8, 32), 256, 0, stream>>>(
        ao, wob, B_ * S_, H_, H_, out, nullptr, nullptr, nullptr, nullptr, nullptr, nullptr);
}

// Round 5
// 208.115 us; speedup vs baseline: 1.1771x; 1.1771x over previous
//
#include <hip/hip_runtime.h>
#include <math.h>

typedef __bf16 bf16;
typedef __attribute__((ext_vector_type(8))) __bf16 bf16x8;
typedef __attribute__((ext_vector_type(4))) __bf16 bf16x4;
typedef __attribute__((ext_vector_type(4))) float f32x4;

#define B_  2
#define S_  2048
#define H_  1024
#define NH_ 16
#define D_  64

__device__ __forceinline__ f32x4 mfma16(bf16x8 a, bf16x8 b, f32x4 c) {
    return __builtin_amdgcn_mfma_f32_16x16x32_bf16(a, b, c, 0, 0, 0);
}

// async global->LDS, 16B per lane; lds dest = wave-uniform base + lane*16
__device__ __forceinline__ void async16(void* lds, const void* g) {
    __builtin_amdgcn_global_load_lds(
        (const __attribute__((address_space(1))) unsigned int*)g,
        (__attribute__((address_space(3))) unsigned int*)lds, 16, 0, 0);
}

// Merged prep: cvt x -> xb, cvt Wqkv -> wqb, build RoPE table tab[s][i]={cos,sin}
__global__ __launch_bounds__(256) void cvt_main(
    const float* __restrict__ x, const float* __restrict__ wqkv,
    bf16* __restrict__ xb, bf16* __restrict__ wqb, float2* __restrict__ tab)
{
    const int bid = blockIdx.x, tid = threadIdx.x;
    if (bid < 4096) {
        int i = bid * 256 + tid;
        f32x4 v = *(const f32x4*)(x + (size_t)i * 4);
        bf16x4 o; o[0]=(bf16)v[0]; o[1]=(bf16)v[1]; o[2]=(bf16)v[2]; o[3]=(bf16)v[3];
        *(bf16x4*)(xb + (size_t)i * 4) = o;
    } else if (bid < 7168) {
        int i = (bid - 4096) * 256 + tid;
        f32x4 v = *(const f32x4*)(wqkv + (size_t)i * 4);
        bf16x4 o; o[0]=(bf16)v[0]; o[1]=(bf16)v[1]; o[2]=(bf16)v[2]; o[3]=(bf16)v[3];
        *(bf16x4*)(wqb + (size_t)i * 4) = o;
    } else {
        int idx = (bid - 7168) * 256 + tid;      // idx = s*32 + i
        int s = idx >> 5, i = idx & 31;
        float f = exp2f((float)i * (-13.287712379549449f / 32.0f));
        float sn, cs;
        sincosf((float)s * f, &sn, &cs);
        tab[idx] = make_float2(cs, sn);
    }
}

// fp32 -> bf16 bulk convert (W_o), 4 elems/thread
__global__ __launch_bounds__(256) void cvt_bf16(const float* __restrict__ src,
                                                bf16* __restrict__ dst, int n4) {
    int i = blockIdx.x * 256 + threadIdx.x;
    if (i >= n4) return;
    f32x4 v = *(const f32x4*)(src + (size_t)i * 4);
    bf16x4 o; o[0]=(bf16)v[0]; o[1]=(bf16)v[1]; o[2]=(bf16)v[2]; o[3]=(bf16)v[3];
    *(bf16x4*)(dst + (size_t)i * 4) = o;
}

// C[M,N] = A[M,K] @ W[N,K]^T, bf16, BK=64 K-tiles (half the barriers of BK=32),
// both tiles via global_load_lds. Tile M=128 x N=NT (128 or 64). LDS rows are
// 64 elems (8 chunks of 16B), XOR-swizzled: phys = logical ^ (row&7).
// EPI=0 (NT=128, qkv): fused RMSNorm + table-RoPE for q/k; lambda-mix + packed
//   transposed store for v. EPI=1: plain fp32 store.
template <int EPI, int NT>
__global__ __launch_bounds__(256) void gemm_bt(
    const bf16* __restrict__ A, const bf16* __restrict__ W,
    int M, int N, int K,
    float* __restrict__ outF,
    bf16* __restrict__ qb, bf16* __restrict__ kb, bf16* __restrict__ vtb,
    const float* __restrict__ ve, const float* __restrict__ lambdas,
    const float2* __restrict__ tab)
{
    constexpr int JN = NT / 32;            // n-subtiles per wave
    __shared__ bf16 Al[128][64];
    __shared__ bf16 Bl[NT][64];
    const int m0   = blockIdx.y * 128;
    const int n0   = blockIdx.x * NT;
    const int tid  = threadIdx.x;
    const int lane = tid & 63;
    const int w    = tid >> 6;
    const int quad = lane >> 4;
    const int l16  = lane & 15;
    const int wm   = (w >> 1) * 64;
    const int wn   = (w & 1) * (NT / 2);
    const int r8   = lane >> 3;                 // row within 8-row group
    const int cs   = ((lane & 7) ^ r8) * 8;     // swizzled source col (elems)

    const f32x4 Z4 = {0.f, 0.f, 0.f, 0.f};
    f32x4 acc[4][JN];
#pragma unroll
    for (int i = 0; i < 4; ++i)
#pragma unroll
        for (int j = 0; j < JN; ++j) acc[i][j] = Z4;

    for (int k0 = 0; k0 < K; k0 += 64) {
        {   // A tile: wave w stages rows [w*32, w*32+32)
            const bf16* gA = A + (size_t)(m0 + w * 32 + r8) * K + k0 + cs;
            async16(&Al[w * 32][0],      gA);
            async16(&Al[w * 32 + 8][0],  gA + (size_t)8  * K);
            async16(&Al[w * 32 + 16][0], gA + (size_t)16 * K);
            async16(&Al[w * 32 + 24][0], gA + (size_t)24 * K);
        }
        if constexpr (NT == 128) {
            const bf16* gB = W + (size_t)(n0 + w * 32 + r8) * K + k0 + cs;
            async16(&Bl[w * 32][0],      gB);
            async16(&Bl[w * 32 + 8][0],  gB + (size_t)8  * K);
            async16(&Bl[w * 32 + 16][0], gB + (size_t)16 * K);
            async16(&Bl[w * 32 + 24][0], gB + (size_t)24 * K);
        } else {
            const bf16* gB = W + (size_t)(n0 + w * 16 + r8) * K + k0 + cs;
            async16(&Bl[w * 16][0],     gB);
            async16(&Bl[w * 16 + 8][0], gB + (size_t)8 * K);
        }
        __syncthreads();
#pragma unroll
        for (int ks = 0; ks < 2; ++ks) {
            bf16x8 af[4], bfg[JN];
#pragma unroll
            for (int i = 0; i < 4; ++i)
                af[i] = *(const bf16x8*)
                    &Al[wm + i * 16 + l16][(((ks << 2) + quad) ^ (l16 & 7)) * 8];
#pragma unroll
            for (int j = 0; j < JN; ++j)
                bfg[j] = *(const bf16x8*)
                    &Bl[wn + j * 16 + l16][(((ks << 2) + quad) ^ (l16 & 7)) * 8];
#pragma unroll
            for (int i = 0; i < 4; ++i)
#pragma unroll
                for (int j = 0; j < JN; ++j)
                    acc[i][j] = mfma16(af[i], bfg[j], acc[i][j]);
        }
        __syncthreads();
    }

    if constexpr (EPI == 1) {
#pragma unroll
        for (int i = 0; i < 4; ++i)
#pragma unroll
            for (int j = 0; j < JN; ++j)
#pragma unroll
                for (int r = 0; r < 4; ++r) {
                    int m = m0 + wm + i * 16 + quad * 4 + r;
                    int n = n0 + wn + j * 16 + l16;
                    outF[(size_t)m * N + n] = acc[i][j][r];
                }
    } else {
        const int nbase = n0 + wn;              // wave-uniform
        const int which = nbase >> 10;          // 0=q 1=k 2=v
        const int h     = (nbase & (H_ - 1)) >> 6;
        if (which < 2) {
            bf16* dst = which ? kb : qb;
#pragma unroll
            for (int i = 0; i < 4; ++i) {
                float ss[4];
#pragma unroll
                for (int r = 0; r < 4; ++r)
                    ss[r] = acc[i][0][r] * acc[i][0][r] + acc[i][1][r] * acc[i][1][r]
                          + acc[i][2][r] * acc[i][2][r] + acc[i][3][r] * acc[i][3][r];
#pragma unroll
                for (int r = 0; r < 4; ++r) {
                    ss[r] += __shfl_xor(ss[r], 1);
                    ss[r] += __shfl_xor(ss[r], 2);
                    ss[r] += __shfl_xor(ss[r], 4);
                    ss[r] += __shfl_xor(ss[r], 8);
                }
#pragma unroll
                for (int r = 0; r < 4; ++r) {
                    int    m   = m0 + wm + i * 16 + quad * 4 + r;
                    int    bb  = m >> 11, s = m & (S_ - 1);
                    float  rms = rsqrtf(ss[r] * (1.0f / 64.0f) + 1.1920929e-07f);
                    float  x0 = acc[i][0][r] * rms, x1 = acc[i][1][r] * rms;
                    float  x2 = acc[i][2][r] * rms, x3 = acc[i][3][r] * rms;
                    float2 t0 = tab[(size_t)s * 32 + l16];        // {cos,sin} i=l16
                    float2 t1 = tab[(size_t)s * 32 + 16 + l16];   // i=l16+16
                    bf16*  bp = dst + ((size_t)(bb * NH_ + h) * S_ + s) * D_;
                    bp[l16]      = (bf16)(x0 * t0.x + x2 * t0.y);
                    bp[16 + l16] = (bf16)(x1 * t1.x + x3 * t1.y);
                    bp[32 + l16] = (bf16)(x2 * t0.x - x0 * t0.y);
                    bp[48 + l16] = (bf16)(x3 * t1.x - x1 * t1.y);
                }
            }
        } else {
            const float l0 = lambdas[0], l1 = lambdas[1];
#pragma unroll
            for (int i = 0; i < 4; ++i) {
                const int m00 = m0 + wm + i * 16 + quad * 4;   // 4 consecutive s
                const int bb  = m00 >> 11, s = m00 & (S_ - 1);
#pragma unroll
                for (int j = 0; j < 4; ++j) {
                    const int d = j * 16 + l16;
                    bf16x4 pk;
#pragma unroll
                    for (int r = 0; r < 4; ++r) {
                        float vm = l0 * acc[i][j][r]
                                 + l1 * ve[(size_t)(m00 + r) * H_ + h * 64 + d];
                        pk[r] = (bf16)vm;
                    }
                    *(bf16x4*)&vtb[((size_t)(bb * NH_ + h) * D_ + d) * S_ + s] = pk;
                }
            }
        }
    }
}

// Flash attention, balanced pairing: block handles q-tiles {bx, 31-bx} -> exactly
// 33 chunks per block (zero tail imbalance). Static max=8, swapped-operand QK
// (scores key-contiguous), double-buffered K/V via global_load_lds (prefetch c+1
// issued before compute of c), diagonal-only causal masking, per-wave P transpose.
__global__ __launch_bounds__(256) void attn(
    const bf16* __restrict__ Q, const bf16* __restrict__ Kg,
    const bf16* __restrict__ Vt, bf16* __restrict__ Og)
{
    __shared__ bf16 Kl[2][64][64];
    __shared__ bf16 Vl[2][64][64];
    __shared__ bf16 Pl[4][16][64];

    const int bh   = blockIdx.y;
    const int b    = bh >> 4;
    const int h    = bh & 15;
    const int tid  = threadIdx.x;
    const int lane = tid & 63;
    const int w    = tid >> 6;
    const int quad = lane >> 4;
    const int l16  = lane & 15;
    const int l7   = l16 & 7;

    const bf16* Qp = Q  + (size_t)bh * S_ * D_;
    const bf16* Kp = Kg + (size_t)bh * S_ * D_;
    const bf16* Vp = Vt + (size_t)bh * D_ * S_;

    const int srow = lane >> 3;
    const int schk = (lane & 7) ^ (lane >> 3);
    const f32x4 Z4 = {0.f, 0.f, 0.f, 0.f};
    const float C1 = 0.18033688011112042f;     // 0.125*log2(e)
    const float C2 = -11.541560327111707f;     // -8*log2(e)

    auto stage = [&](int p, int kb0) {
        const bf16* gK = Kp + (size_t)(kb0 + w * 16 + srow) * D_ + schk * 8;
        async16(&Kl[p][w * 16][0], gK);
        async16(&Kl[p][w * 16 + 8][0], gK + (size_t)8 * D_);
        const bf16* gV = Vp + (size_t)(w * 16 + srow) * S_ + kb0 + schk * 8;
        async16(&Vl[p][w * 16][0], gV);
        async16(&Vl[p][w * 16 + 8][0], gV + (size_t)8 * S_);
    };

    for (int half = 0; half < 2; ++half) {
        const int qt    = half ? (31 - blockIdx.x) : blockIdx.x;
        const int qbase = qt * 64 + w * 16;
        const int qi    = qbase + l16;

        bf16x8 qf0 = *(const bf16x8*)(Qp + (size_t)(qbase + l16) * D_ + quad * 8);
        bf16x8 qf1 = *(const bf16x8*)(Qp + (size_t)(qbase + l16) * D_ + 32 + quad * 8);

        f32x4 of[4];
#pragma unroll
        for (int dt = 0; dt < 4; ++dt) of[dt] = Z4;
        float lsum = 0.f;

        const int nch = qt + 1;
        __syncthreads();           // prev half's compute done before restaging buf0
        stage(0, 0);
        for (int c = 0; c < nch; ++c) {
            const int p   = c & 1;
            const int kb0 = c * 64;
            __syncthreads();                 // buf[p] ready (prefetch aged 1 phase)
            if (c + 1 < nch) stage(p ^ 1, kb0 + 64);

            float ps = 0.f;
            if (c < qt) {                    // strictly below diagonal: no mask
#pragma unroll
                for (int nt = 0; nt < 4; ++nt) {
                    bf16x8 kf0 = *(const bf16x8*)&Kl[p][nt * 16 + l16][(quad ^ l7) * 8];
                    bf16x8 kf1 = *(const bf16x8*)&Kl[p][nt * 16 + l16][((quad + 4) ^ l7) * 8];
                    f32x4 sacc = Z4;
                    sacc = mfma16(kf0, qf0, sacc);
                    sacc = mfma16(kf1, qf1, sacc);
                    bf16x4 pk;
#pragma unroll
                    for (int r = 0; r < 4; ++r) {
                        float pv = exp2f(fmaf(sacc[r], C1, C2));
                        ps += pv;
                        pk[r] = (bf16)pv;
                    }
                    *(bf16x4*)&Pl[w][l16][((nt * 2 + (quad >> 1)) ^ l7) * 8 + (quad & 1) * 4] = pk;
                }
            } else {                         // diagonal chunk: causal mask
#pragma unroll
                for (int nt = 0; nt < 4; ++nt) {
                    bf16x8 kf0 = *(const bf16x8*)&Kl[p][nt * 16 + l16][(quad ^ l7) * 8];
                    bf16x8 kf1 = *(const bf16x8*)&Kl[p][nt * 16 + l16][((quad + 4) ^ l7) * 8];
                    f32x4 sacc = Z4;
                    sacc = mfma16(kf0, qf0, sacc);
                    sacc = mfma16(kf1, qf1, sacc);
                    bf16x4 pk;
#pragma unroll
                    for (int r = 0; r < 4; ++r) {
                        int   key = kb0 + nt * 16 + quad * 4 + r;
                        float pv  = (key <= qi) ? exp2f(fmaf(sacc[r], C1, C2)) : 0.f;
                        ps += pv;
                        pk[r] = (bf16)pv;
                    }
                    *(bf16x4*)&Pl[w][l16][((nt * 2 + (quad >> 1)) ^ l7) * 8 + (quad & 1) * 4] = pk;
                }
            }
            ps += __shfl_xor(ps, 16);
            ps += __shfl_xor(ps, 32);
            lsum += ps;

            bf16x8 pf0 = *(const bf16x8*)&Pl[w][l16][(quad ^ l7) * 8];
            bf16x8 pf1 = *(const bf16x8*)&Pl[w][l16][((quad + 4) ^ l7) * 8];
#pragma unroll
            for (int dt = 0; dt < 4; ++dt) {
                bf16x8 vf0 = *(const bf16x8*)&Vl[p][dt * 16 + l16][(quad ^ l7) * 8];
                bf16x8 vf1 = *(const bf16x8*)&Vl[p][dt * 16 + l16][((quad + 4) ^ l7) * 8];
                of[dt] = mfma16(pf0, vf0, of[dt]);
                of[dt] = mfma16(pf1, vf1, of[dt]);
            }
        }

#pragma unroll
        for (int r = 0; r < 4; ++r) {
            float ld = __shfl(lsum, quad * 4 + r);
            float rl = 1.0f / ld;
            int   qq = qbase + quad * 4 + r;
#pragma unroll
            for (int dt = 0; dt < 4; ++dt)
                Og[((size_t)(b * S_ + qq)) * H_ + h * D_ + dt * 16 + l16] =
                    (bf16)(of[dt][r] * rl);
        }
    }
}

extern "C" void kernel_launch(void* const* d_in, const int* in_sizes, int n_in,
                              void* d_out, int out_size, void* d_ws, size_t ws_size,
                              hipStream_t stream)
{
    const float* x       = (const float*)d_in[0];
    const float* ve      = (const float*)d_in[1];
    const float* Wqkv    = (const float*)d_in[2];
    const float* Wo      = (const float*)d_in[3];
    const float* lambdas = (const float*)d_in[4];
    float* out = (float*)d_out;

    // d_out (16 MiB) early-phase scratch: xb [0,8M), wqb [8,14M), rope tab [14,14.5M).
    // All die after gemm1; gemm2 overwrites d_out with the final output.
    // ws (32 MiB): qb [0,8M), kb [8,16M), vtb [16,24M), ao [24,32M);
    // wob reuses [0,2M) after attn retires qb.
    char* od = (char*)d_out;
    char* ws = (char*)d_ws;
    const size_t MB = 1024 * 1024;
    bf16*   xb  = (bf16*)(od);
    bf16*   wqb = (bf16*)(od + 8 * MB);
    float2* tab = (float2*)(od + 14 * MB);
    bf16*   qb  = (bf16*)(ws);
    bf16*   kb  = (bf16*)(ws + 8 * MB);
    bf16*   vtb = (bf16*)(ws + 16 * MB);
    bf16*   ao  = (bf16*)(ws + 24 * MB);
    bf16*   wob = (bf16*)(ws);

    // 1) convert x + W_qkv to bf16, build RoPE table (one kernel)
    cvt_main<<<7424, 256, 0, stream>>>(x, Wqkv, xb, wqb, tab);
    // 2) qkv GEMM (BK=64), fused RMSNorm + table-RoPE (q,k) + packed lambda-mix (v)
    gemm_bt<0, 128><<<dim3(24, 32), 256, 0, stream>>>(
        xb, wqb, B_ * S_, 3 * H_, H_, nullptr, qb, kb, vtb, ve, lambdas, (const float2*)tab);
    // 3) balanced causal flash attention -> ao
    attn<<<dim3(16, B_ * NH_), 256, 0, stream>>>(qb, kb, vtb, ao);
    // 4) convert W_o (into retired qb space)
    cvt_bf16<<<1024, 256, 0, stream>>>(Wo, wob, (H_ * H_) / 4);
    // 5) out = ao @ Wo^T (BK=64, 128x64 tiles, 2 blocks/CU, fp32 out)
    gemm_bt<1, 64><<<dim3(16, 32), 256, 0, stream>>>(
        ao, wob, B_ * S_, H_, H_, out, nullptr, nullptr, nullptr, nullptr, nullptr, nullptr);
}